// Round 7
// baseline (355.941 us; speedup 1.0000x reference)
//
#include <hip/hip_runtime.h>
#include <hip/hip_bf16.h>
#include <stdint.h>

typedef unsigned short u16;
typedef __attribute__((ext_vector_type(8))) short bf16x8;
typedef __attribute__((ext_vector_type(4))) short bf16x4;
typedef __attribute__((ext_vector_type(4))) float f32x4;

__device__ __forceinline__ float bf2f(u16 u) {
    union { unsigned int i; float f; } v; v.i = ((unsigned int)u) << 16; return v.f;
}
__device__ __forceinline__ u16 f2bf(float f) {
    union { float f; unsigned int i; } v; v.f = f;
    unsigned int x = v.i;
    return (u16)((x + 0x7fffu + ((x >> 16) & 1u)) >> 16);
}
__device__ __forceinline__ unsigned fbits(float f) {
    union { float f; unsigned int i; } v; v.f = f; return v.i;
}
__device__ __forceinline__ void async16(const void* g, void* lds) {
    __builtin_amdgcn_global_load_lds((const __attribute__((address_space(1))) void*)g,
                                     (__attribute__((address_space(3))) void*)lds,
                                     16, 0, 0);
}

#define QSCALE 0.18033688f  /* 0.125 * log2(e): folded into Q so attn uses bare exp2 */

// ---------------------------------------------------------------------------
// prep: blocks 0..1023 transpose+convert the 4 weights (Wt[n][k]=bf16(W[k][n]));
//       blocks 1024..3071 convert tgt/memory fp32->bf16.
// ---------------------------------------------------------------------------
__global__ __launch_bounds__(256) void prep(
    const float* __restrict__ tgt, const float* __restrict__ mem,
    const float* __restrict__ Wq, const float* __restrict__ Wk,
    const float* __restrict__ Wv, const float* __restrict__ Wo,
    u16* __restrict__ Wt, u16* __restrict__ tgtb, u16* __restrict__ memb)
{
    __shared__ u16 tile[64][65];
    const int id = blockIdx.x;
    const int tid = threadIdx.x;
    if (id < 1024) {
        const int z = id >> 8;
        const float* in = (z == 0) ? Wq : (z == 1) ? Wk : (z == 2) ? Wv : Wo;
        u16* out = Wt + (size_t)z * 1048576;
        const int k0 = (id & 15) * 64, n0 = ((id >> 4) & 15) * 64;
        const int r = tid >> 2, c0 = (tid & 3) << 4;
#pragma unroll
        for (int i = 0; i < 4; ++i) {
            float4 v = *(const float4*)&in[(size_t)(k0 + r) * 1024 + n0 + c0 + i * 4];
            tile[c0 + i * 4 + 0][r] = f2bf(v.x);
            tile[c0 + i * 4 + 1][r] = f2bf(v.y);
            tile[c0 + i * 4 + 2][r] = f2bf(v.z);
            tile[c0 + i * 4 + 3][r] = f2bf(v.w);
        }
        __syncthreads();
#pragma unroll
        for (int i = 0; i < 2; ++i) {
            bf16x8 v;
#pragma unroll
            for (int j = 0; j < 8; ++j) v[j] = (short)tile[r][c0 + i * 8 + j];
            *(bf16x8*)&out[(size_t)(n0 + r) * 1024 + k0 + c0 + i * 8] = v;
        }
    } else {
        size_t i = ((size_t)(id - 1024) * 256 + tid) * 8;
        float4 a0 = *(const float4*)&tgt[i];
        float4 a1 = *(const float4*)&tgt[i + 4];
        float4 b0 = *(const float4*)&mem[i];
        float4 b1 = *(const float4*)&mem[i + 4];
        bf16x8 va, vb;
        va[0] = (short)f2bf(a0.x); va[1] = (short)f2bf(a0.y);
        va[2] = (short)f2bf(a0.z); va[3] = (short)f2bf(a0.w);
        va[4] = (short)f2bf(a1.x); va[5] = (short)f2bf(a1.y);
        va[6] = (short)f2bf(a1.z); va[7] = (short)f2bf(a1.w);
        vb[0] = (short)f2bf(b0.x); vb[1] = (short)f2bf(b0.y);
        vb[2] = (short)f2bf(b0.z); vb[3] = (short)f2bf(b0.w);
        vb[4] = (short)f2bf(b1.x); vb[5] = (short)f2bf(b1.y);
        vb[6] = (short)f2bf(b1.z); vb[7] = (short)f2bf(b1.w);
        *(bf16x8*)&tgtb[i] = va;
        *(bf16x8*)&memb[i] = vb;
    }
}

// ---------------------------------------------------------------------------
// QKV GEMM (R5 version): 128x128 tile, BK=32, single-buffered, XOR-swizzled.
// z==0: Q (scaled by QSCALE); z==1: K; z==2: V written transposed to Vt.
// ---------------------------------------------------------------------------
__global__ __launch_bounds__(256) void gemm_qkv(
    const u16* __restrict__ tgtb, const u16* __restrict__ memb,
    const u16* __restrict__ Wt,
    const float* __restrict__ bq, const float* __restrict__ bk, const float* __restrict__ bv,
    u16* __restrict__ Qb, u16* __restrict__ Kb, u16* __restrict__ Vtb)
{
    __shared__ __align__(16) u16 sA[128 * 32];
    __shared__ __align__(16) u16 sB[128 * 32];
    const int z = blockIdx.z;
    const u16* A = (z == 0) ? tgtb : memb;
    const u16* Bt = Wt + (size_t)z * 1048576;
    const float* bias = (z == 0) ? bq : (z == 1) ? bk : bv;

    const int tid = threadIdx.x;
    const int wave = tid >> 6, lane = tid & 63;
    const int quad = lane >> 4, l16 = lane & 15;
    const int m0 = blockIdx.x * 128, n0 = blockIdx.y * 128;
    const int wm = (wave & 1) * 64, wn = (wave >> 1) * 64;
    const int sw = (quad ^ ((l16 >> 1) & 3)) << 3;

    f32x4 acc[4][4] = {};

    for (int k0 = 0; k0 < 1024; k0 += 32) {
        __syncthreads();
#pragma unroll
        for (int r = 0; r < 2; ++r) {
            int c = tid + r * 256;
            int g = (c & 3) ^ ((c >> 3) & 3);
            const u16* gA = A + (size_t)(m0 + (c >> 2)) * 1024 + k0 + g * 8;
            async16(gA, (char*)sA + r * 4096 + wave * 1024);
            const u16* gB = Bt + (size_t)(n0 + (c >> 2)) * 1024 + k0 + g * 8;
            async16(gB, (char*)sB + r * 4096 + wave * 1024);
        }
        __syncthreads();
        bf16x8 af[4], bfr[4];
#pragma unroll
        for (int i = 0; i < 4; ++i) {
            af[i]  = *(const bf16x8*)&sA[(wm + i * 16 + l16) * 32 + sw];
            bfr[i] = *(const bf16x8*)&sB[(wn + i * 16 + l16) * 32 + sw];
        }
#pragma unroll
        for (int i = 0; i < 4; ++i)
#pragma unroll
            for (int j = 0; j < 4; ++j)
                acc[i][j] = __builtin_amdgcn_mfma_f32_16x16x32_bf16(af[i], bfr[j], acc[i][j], 0, 0, 0);
    }

    if (z == 2) {
#pragma unroll
        for (int j = 0; j < 4; ++j) {
            int n = n0 + wn + j * 16 + l16;
            float bb = bias[n];
            int d = n & 63;
#pragma unroll
            for (int i = 0; i < 4; ++i) {
                int mb = m0 + wm + i * 16 + quad * 4;
                int bh = (mb >> 11) * 16 + (n >> 6);
                bf16x4 pk;
#pragma unroll
                for (int r = 0; r < 4; ++r) pk[r] = (short)f2bf(acc[i][j][r] + bb);
                *(bf16x4*)&Vtb[(size_t)bh * 131072 + (size_t)d * 2048 + (mb & 2047)] = pk;
            }
        }
    } else {
        u16* C = (z == 0) ? Qb : Kb;
        const float scl = (z == 0) ? QSCALE : 1.0f;
#pragma unroll
        for (int j = 0; j < 4; ++j) {
            int n = n0 + wn + j * 16 + l16;
            float bb = bias[n];
#pragma unroll
            for (int i = 0; i < 4; ++i) {
                int mb = m0 + wm + i * 16 + quad * 4;
#pragma unroll
                for (int r = 0; r < 4; ++r)
                    C[(size_t)(mb + r) * 1024 + n] = f2bf((acc[i][j][r] + bb) * scl);
            }
        }
    }
}

// ---------------------------------------------------------------------------
// Output GEMM (R5 version): 64x128 tile, single-buffered, fp32 out.
// ---------------------------------------------------------------------------
__global__ __launch_bounds__(256) void gemm_out(
    const u16* __restrict__ A, const u16* __restrict__ Bt,
    const float* __restrict__ bias, float* __restrict__ C)
{
    __shared__ __align__(16) u16 sA[64 * 32];
    __shared__ __align__(16) u16 sB[128 * 32];
    const int tid = threadIdx.x;
    const int wave = tid >> 6, lane = tid & 63;
    const int quad = lane >> 4, l16 = lane & 15;
    const int m0 = blockIdx.x * 64, n0 = blockIdx.y * 128;
    const int wm = (wave & 1) * 32, wn = (wave >> 1) * 64;
    const int sw = (quad ^ ((l16 >> 1) & 3)) << 3;
    f32x4 acc[2][4] = {};

    for (int k0 = 0; k0 < 1024; k0 += 32) {
        __syncthreads();
        {
            int c = tid;
            int g = (c & 3) ^ ((c >> 3) & 3);
            const u16* gA = A + (size_t)(m0 + (c >> 2)) * 1024 + k0 + g * 8;
            async16(gA, (char*)sA + wave * 1024);
        }
#pragma unroll
        for (int r = 0; r < 2; ++r) {
            int c = tid + r * 256;
            int g = (c & 3) ^ ((c >> 3) & 3);
            const u16* gB = Bt + (size_t)(n0 + (c >> 2)) * 1024 + k0 + g * 8;
            async16(gB, (char*)sB + r * 4096 + wave * 1024);
        }
        __syncthreads();
        bf16x8 af[2], bfr[4];
#pragma unroll
        for (int i = 0; i < 2; ++i)
            af[i] = *(const bf16x8*)&sA[(wm + i * 16 + l16) * 32 + sw];
#pragma unroll
        for (int j = 0; j < 4; ++j)
            bfr[j] = *(const bf16x8*)&sB[(wn + j * 16 + l16) * 32 + sw];
#pragma unroll
        for (int i = 0; i < 2; ++i)
#pragma unroll
            for (int j = 0; j < 4; ++j)
                acc[i][j] = __builtin_amdgcn_mfma_f32_16x16x32_bf16(af[i], bfr[j], acc[i][j], 0, 0, 0);
    }
#pragma unroll
    for (int j = 0; j < 4; ++j) {
        int n = n0 + wn + j * 16 + l16;
        float bb = bias[n];
#pragma unroll
        for (int i = 0; i < 2; ++i) {
            int mb = m0 + wm + i * 16 + quad * 4;
#pragma unroll
            for (int r = 0; r < 4; ++r)
                C[(size_t)(mb + r) * 1024 + n] = acc[i][j][r] + bb;
        }
    }
}

// ---------------------------------------------------------------------------
// Attention v4: kv-split, WAVE-PRIVATE LDS staging, NO barrier in main loop.
// Block: 256 thr / 4 waves; one (bh, 64-q tile). Wave w owns kv in
// [w*512, (w+1)*512), iterated as 32 tiles of 16 kv (start staggered by qt).
// Each wave stages its own K-slice (2KB) and V^T-slice (2KB) into private
// double-buffered LDS via async16 and syncs with explicit
// s_waitcnt vmcnt(4) -- AITER-style fine-grained pipeline, possible here
// because no LDS is shared between waves.
// Per 16-kv iter: S^T = K@Q^T (x32 MFMA, C-layout row=kv col=q) -> exp2 ->
// pack P^T in-register as B-frag -> O^T += V^T@P^T (16x16x16).
// Epilogue: shfl rowsum per wave + cross-wave O reduce via LDS (staging pool
// reused as fp32 reduce buffer).
// ---------------------------------------------------------------------------
__global__ __launch_bounds__(256, 4) void attn_kernel(
    const u16* __restrict__ Q,   // (B*T) x 1024, pre-scaled by QSCALE
    const u16* __restrict__ K,   // (B*T) x 1024
    const u16* __restrict__ Vt,  // (B*H) x 64 x 2048
    u16* __restrict__ Y)         // (B*T) x 1024
{
    // pool: main loop = per-wave staging (K: [0,16K) bytes, V: [16K,32K));
    //       epilogue = fp32 O^T reduce buffer [0,16K).
    __shared__ __align__(16) char pool[32768];
    __shared__ float wsum[4][64];

    const int tid = threadIdx.x;
    const int wave = tid >> 6, lane = tid & 63;
    const int quad = lane >> 4, l16 = lane & 15;

    const int bidx = blockIdx.x;
    const int bh = (bidx & 7) * 4 + ((bidx >> 3) & 3);   // XCD swizzle
    const int qt = bidx >> 5;            // 0..31
    const int b = bh >> 4, h = bh & 15;
    const size_t qrow0 = (size_t)b * 2048 + qt * 64;

    // Q B-frags for all 4 q-subtiles: n=q=nt*16+l16, k=d
    bf16x8 qf[4][2];
#pragma unroll
    for (int nt = 0; nt < 4; ++nt)
#pragma unroll
        for (int kf = 0; kf < 2; ++kf)
            qf[nt][kf] = *(const bf16x8*)&Q[(qrow0 + nt * 16 + l16) * 1024 + h * 64 + kf * 32 + quad * 8];

    f32x4 oacc[4][4] = {};   // [mt=d-tile][nt=q-tile]
    float racc[4] = {0.f, 0.f, 0.f, 0.f};

    const u16* Kbase = K + (size_t)b * 2048 * 1024 + h * 64;
    const u16* Vbase = Vt + (size_t)bh * 131072;

    // wave-private staging buffers
    char* kbuf0 = pool + (wave * 2 + 0) * 2048;
    char* kbuf1 = pool + (wave * 2 + 1) * 2048;
    char* vbuf0 = pool + 16384 + (wave * 2 + 0) * 2048;
    char* vbuf1 = pool + 16384 + (wave * 2 + 1) * 2048;

    // per-thread staging offsets (elements)
    // K slice: 16 rows(kv) x 64 d; chunk swizzle c' = c ^ (row&7)
    const size_t kgo = (size_t)(lane >> 3) * 1024 + (size_t)(((lane & 7) ^ ((lane >> 3) & 7)) * 8);
    // V^T slice: 64 rows(d) x 16 kv (2 chunks/row); swizzle p = c ^ (d&1)
    const size_t vgo = (size_t)(lane >> 1) * 2048 + (size_t)((((lane & 1) ^ ((lane >> 1) & 1))) * 8);

    // LDS read offsets (u16 elements)
    const int koff0 = l16 * 64 + ((0 * 4 + quad) ^ (l16 & 7)) * 8;
    const int koff1 = l16 * 64 + ((1 * 4 + quad) ^ (l16 & 7)) * 8;
    int voff[4];
#pragma unroll
    for (int mt = 0; mt < 4; ++mt)
        voff[mt] = (mt * 16 + l16) * 16 + (((quad >> 1) ^ (l16 & 1)) * 8) + (quad & 1) * 4;

    const int base_kv = wave * 512;

#define ASTAGE(t, kb, vb)                                                        \
    {                                                                            \
        const int kv0 = base_kv + ((qt + (t)) & 31) * 16;                        \
        async16(Kbase + (size_t)kv0 * 1024 + kgo, (kb) + lane * 16);             \
        async16(Kbase + (size_t)(kv0 + 8) * 1024 + kgo, (kb) + 1024 + lane * 16);\
        async16(Vbase + (size_t)kv0 + vgo, (vb) + lane * 16);                    \
        async16(Vbase + (size_t)kv0 + vgo + 32 * 2048, (vb) + 1024 + lane * 16); \
    }

    ASTAGE(0, kbuf0, vbuf0);

    for (int i = 0; i < 32; ++i) {
        // prefetch next tile into the other buffer (i==31 restages tile 0: harmless)
        if (i & 1) ASTAGE(i + 1, kbuf0, vbuf0) else ASTAGE(i + 1, kbuf1, vbuf1);
        __builtin_amdgcn_s_waitcnt(0x0F74);   // vmcnt(4): stage(i) landed
        const u16* kb = (const u16*)((i & 1) ? kbuf1 : kbuf0);
        const u16* vb = (const u16*)((i & 1) ? vbuf1 : vbuf0);
        bf16x8 ka0 = *(const bf16x8*)&kb[koff0];
        bf16x8 ka1 = *(const bf16x8*)&kb[koff1];
        bf16x4 vf[4];
#pragma unroll
        for (int mt = 0; mt < 4; ++mt)
            vf[mt] = *(const bf16x4*)&vb[voff[mt]];
#pragma unroll
        for (int nt = 0; nt < 4; ++nt) {
            f32x4 s = {0.f, 0.f, 0.f, 0.f};
            s = __builtin_amdgcn_mfma_f32_16x16x32_bf16(ka0, qf[nt][0], s, 0, 0, 0);
            s = __builtin_amdgcn_mfma_f32_16x16x32_bf16(ka1, qf[nt][1], s, 0, 0, 0);
            float p0 = __builtin_amdgcn_exp2f(s[0]);
            float p1 = __builtin_amdgcn_exp2f(s[1]);
            float p2 = __builtin_amdgcn_exp2f(s[2]);
            float p3 = __builtin_amdgcn_exp2f(s[3]);
            racc[nt] += (p0 + p1) + (p2 + p3);
            unsigned lo = __builtin_amdgcn_perm(fbits(p1) + 0x8000u, fbits(p0) + 0x8000u, 0x07060302u);
            unsigned hi = __builtin_amdgcn_perm(fbits(p3) + 0x8000u, fbits(p2) + 0x8000u, 0x07060302u);
            union { unsigned u[2]; bf16x4 v; } pku;
            pku.u[0] = lo; pku.u[1] = hi;
#pragma unroll
            for (int mt = 0; mt < 4; ++mt)
                oacc[mt][nt] = __builtin_amdgcn_mfma_f32_16x16x16bf16_1k(vf[mt], pku.v, oacc[mt][nt], 0, 0, 0);
        }
    }
#undef ASTAGE

    // drain the dummy stage before reusing the pool
    __builtin_amdgcn_s_waitcnt(0x0F70);   // vmcnt(0)
    __syncthreads();

    // rowsum: reduce over quads; wave-partial to wsum
#pragma unroll
    for (int nt = 0; nt < 4; ++nt) {
        float r = racc[nt];
        r += __shfl_xor(r, 16, 64);
        r += __shfl_xor(r, 32, 64);
        if (quad == 0) wsum[wave][nt * 16 + l16] = r;
    }

    // O^T cross-wave reduce in the reused pool
    float* osh = (float*)pool;   // [d][q] 64x64 fp32
    for (int idx = tid; idx < 4096; idx += 256) osh[idx] = 0.0f;
    __syncthreads();
#pragma unroll
    for (int mt = 0; mt < 4; ++mt)
#pragma unroll
        for (int nt = 0; nt < 4; ++nt)
#pragma unroll
            for (int r = 0; r < 4; ++r)
                atomicAdd(&osh[(mt * 16 + quad * 4 + r) * 64 + nt * 16 + l16], oacc[mt][nt][r]);
    __syncthreads();

    // writeout: thread -> (q = tid&63, dblk = tid>>6), 16 d-values, 2x16B
    {
        const int q = tid & 63, dblk = tid >> 6;
        float inv = 1.0f / (wsum[0][q] + wsum[1][q] + wsum[2][q] + wsum[3][q]);
        bf16x8 o0, o1;
#pragma unroll
        for (int j = 0; j < 8; ++j) {
            o0[j] = (short)f2bf(osh[(dblk * 16 + j) * 64 + q] * inv);
            o1[j] = (short)f2bf(osh[(dblk * 16 + 8 + j) * 64 + q] * inv);
        }
        u16* yp = &Y[(qrow0 + q) * 1024 + h * 64 + dblk * 16];
        *(bf16x8*)yp = o0;
        *(bf16x8*)(yp + 8) = o1;
    }
}

// ---------------------------------------------------------------------------
extern "C" void kernel_launch(void* const* d_in, const int* in_sizes, int n_in,
                              void* d_out, int out_size, void* d_ws, size_t ws_size,
                              hipStream_t stream) {
    const float* tgt = (const float*)d_in[0];
    const float* mem = (const float*)d_in[1];
    const float* Wq  = (const float*)d_in[2];
    const float* bq  = (const float*)d_in[3];
    const float* Wk  = (const float*)d_in[4];
    const float* bk  = (const float*)d_in[5];
    const float* Wv  = (const float*)d_in[6];
    const float* bv  = (const float*)d_in[7];
    const float* Wo  = (const float*)d_in[8];
    const float* bo  = (const float*)d_in[9];

    u16* ws = (u16*)d_ws;
    const size_t SZ = 4194304;          // elements per 4096x1024 bf16 buffer
    u16* Wt   = ws;                     // 4 x 1024x1024 bf16 (8 MB)
    u16* tgtb = ws + 4 * SZ;
    u16* memb = tgtb + SZ;
    u16* Qb   = memb + SZ;
    u16* Kb   = Qb + SZ;
    u16* Vtb  = Kb + SZ;                // 32 x 64 x 2048
    u16* Yb   = Vtb + SZ;
    float* out = (float*)d_out;

    prep<<<dim3(3072), 256, 0, stream>>>(tgt, mem, Wq, Wk, Wv, Wo, Wt, tgtb, memb);
    gemm_qkv<<<dim3(32, 8, 3), 256, 0, stream>>>(tgtb, memb, Wt, bq, bk, bv, Qb, Kb, Vtb);
    attn_kernel<<<dim3(1024), 256, 0, stream>>>(Qb, Kb, Vtb, Yb);
    gemm_out<<<dim3(64, 8), 256, 0, stream>>>(Yb, Wt + 3 * (size_t)1048576, bo, out);
}

// Round 8
// 226.130 us; speedup vs baseline: 1.5741x; 1.5741x over previous
//
#include <hip/hip_runtime.h>
#include <hip/hip_bf16.h>
#include <stdint.h>

typedef unsigned short u16;
typedef __attribute__((ext_vector_type(8))) short bf16x8;
typedef __attribute__((ext_vector_type(4))) short bf16x4;
typedef __attribute__((ext_vector_type(4))) float f32x4;

__device__ __forceinline__ float bf2f(u16 u) {
    union { unsigned int i; float f; } v; v.i = ((unsigned int)u) << 16; return v.f;
}
__device__ __forceinline__ u16 f2bf(float f) {
    union { float f; unsigned int i; } v; v.f = f;
    unsigned int x = v.i;
    return (u16)((x + 0x7fffu + ((x >> 16) & 1u)) >> 16);
}
__device__ __forceinline__ unsigned fbits(float f) {
    union { float f; unsigned int i; } v; v.f = f; return v.i;
}
__device__ __forceinline__ void async16(const void* g, void* lds) {
    __builtin_amdgcn_global_load_lds((const __attribute__((address_space(1))) void*)g,
                                     (__attribute__((address_space(3))) void*)lds,
                                     16, 0, 0);
}

#define QSCALE 0.18033688f  /* 0.125 * log2(e): folded into Q so attn uses bare exp2 */

// ---------------------------------------------------------------------------
// prep: blocks 0..1023 transpose+convert the 4 weights (Wt[n][k]=bf16(W[k][n]));
//       blocks 1024..3071 convert tgt/memory fp32->bf16.
// ---------------------------------------------------------------------------
__global__ __launch_bounds__(256) void prep(
    const float* __restrict__ tgt, const float* __restrict__ mem,
    const float* __restrict__ Wq, const float* __restrict__ Wk,
    const float* __restrict__ Wv, const float* __restrict__ Wo,
    u16* __restrict__ Wt, u16* __restrict__ tgtb, u16* __restrict__ memb)
{
    __shared__ u16 tile[64][65];
    const int id = blockIdx.x;
    const int tid = threadIdx.x;
    if (id < 1024) {
        const int z = id >> 8;
        const float* in = (z == 0) ? Wq : (z == 1) ? Wk : (z == 2) ? Wv : Wo;
        u16* out = Wt + (size_t)z * 1048576;
        const int k0 = (id & 15) * 64, n0 = ((id >> 4) & 15) * 64;
        const int r = tid >> 2, c0 = (tid & 3) << 4;
#pragma unroll
        for (int i = 0; i < 4; ++i) {
            float4 v = *(const float4*)&in[(size_t)(k0 + r) * 1024 + n0 + c0 + i * 4];
            tile[c0 + i * 4 + 0][r] = f2bf(v.x);
            tile[c0 + i * 4 + 1][r] = f2bf(v.y);
            tile[c0 + i * 4 + 2][r] = f2bf(v.z);
            tile[c0 + i * 4 + 3][r] = f2bf(v.w);
        }
        __syncthreads();
#pragma unroll
        for (int i = 0; i < 2; ++i) {
            bf16x8 v;
#pragma unroll
            for (int j = 0; j < 8; ++j) v[j] = (short)tile[r][c0 + i * 8 + j];
            *(bf16x8*)&out[(size_t)(n0 + r) * 1024 + k0 + c0 + i * 8] = v;
        }
    } else {
        size_t i = ((size_t)(id - 1024) * 256 + tid) * 8;
        float4 a0 = *(const float4*)&tgt[i];
        float4 a1 = *(const float4*)&tgt[i + 4];
        float4 b0 = *(const float4*)&mem[i];
        float4 b1 = *(const float4*)&mem[i + 4];
        bf16x8 va, vb;
        va[0] = (short)f2bf(a0.x); va[1] = (short)f2bf(a0.y);
        va[2] = (short)f2bf(a0.z); va[3] = (short)f2bf(a0.w);
        va[4] = (short)f2bf(a1.x); va[5] = (short)f2bf(a1.y);
        va[6] = (short)f2bf(a1.z); va[7] = (short)f2bf(a1.w);
        vb[0] = (short)f2bf(b0.x); vb[1] = (short)f2bf(b0.y);
        vb[2] = (short)f2bf(b0.z); vb[3] = (short)f2bf(b0.w);
        vb[4] = (short)f2bf(b1.x); vb[5] = (short)f2bf(b1.y);
        vb[6] = (short)f2bf(b1.z); vb[7] = (short)f2bf(b1.w);
        *(bf16x8*)&tgtb[i] = va;
        *(bf16x8*)&memb[i] = vb;
    }
}

// ---------------------------------------------------------------------------
// QKV GEMM (R5 version): 128x128 tile, BK=32, single-buffered, XOR-swizzled.
// z==0: Q (scaled by QSCALE); z==1: K; z==2: V written transposed to Vt.
// ---------------------------------------------------------------------------
__global__ __launch_bounds__(256) void gemm_qkv(
    const u16* __restrict__ tgtb, const u16* __restrict__ memb,
    const u16* __restrict__ Wt,
    const float* __restrict__ bq, const float* __restrict__ bk, const float* __restrict__ bv,
    u16* __restrict__ Qb, u16* __restrict__ Kb, u16* __restrict__ Vtb)
{
    __shared__ __align__(16) u16 sA[128 * 32];
    __shared__ __align__(16) u16 sB[128 * 32];
    const int z = blockIdx.z;
    const u16* A = (z == 0) ? tgtb : memb;
    const u16* Bt = Wt + (size_t)z * 1048576;
    const float* bias = (z == 0) ? bq : (z == 1) ? bk : bv;

    const int tid = threadIdx.x;
    const int wave = tid >> 6, lane = tid & 63;
    const int quad = lane >> 4, l16 = lane & 15;
    const int m0 = blockIdx.x * 128, n0 = blockIdx.y * 128;
    const int wm = (wave & 1) * 64, wn = (wave >> 1) * 64;
    const int sw = (quad ^ ((l16 >> 1) & 3)) << 3;

    f32x4 acc[4][4] = {};

    for (int k0 = 0; k0 < 1024; k0 += 32) {
        __syncthreads();
#pragma unroll
        for (int r = 0; r < 2; ++r) {
            int c = tid + r * 256;
            int g = (c & 3) ^ ((c >> 3) & 3);
            const u16* gA = A + (size_t)(m0 + (c >> 2)) * 1024 + k0 + g * 8;
            async16(gA, (char*)sA + r * 4096 + wave * 1024);
            const u16* gB = Bt + (size_t)(n0 + (c >> 2)) * 1024 + k0 + g * 8;
            async16(gB, (char*)sB + r * 4096 + wave * 1024);
        }
        __syncthreads();
        bf16x8 af[4], bfr[4];
#pragma unroll
        for (int i = 0; i < 4; ++i) {
            af[i]  = *(const bf16x8*)&sA[(wm + i * 16 + l16) * 32 + sw];
            bfr[i] = *(const bf16x8*)&sB[(wn + i * 16 + l16) * 32 + sw];
        }
#pragma unroll
        for (int i = 0; i < 4; ++i)
#pragma unroll
            for (int j = 0; j < 4; ++j)
                acc[i][j] = __builtin_amdgcn_mfma_f32_16x16x32_bf16(af[i], bfr[j], acc[i][j], 0, 0, 0);
    }

    if (z == 2) {
#pragma unroll
        for (int j = 0; j < 4; ++j) {
            int n = n0 + wn + j * 16 + l16;
            float bb = bias[n];
            int d = n & 63;
#pragma unroll
            for (int i = 0; i < 4; ++i) {
                int mb = m0 + wm + i * 16 + quad * 4;
                int bh = (mb >> 11) * 16 + (n >> 6);
                bf16x4 pk;
#pragma unroll
                for (int r = 0; r < 4; ++r) pk[r] = (short)f2bf(acc[i][j][r] + bb);
                *(bf16x4*)&Vtb[(size_t)bh * 131072 + (size_t)d * 2048 + (mb & 2047)] = pk;
            }
        }
    } else {
        u16* C = (z == 0) ? Qb : Kb;
        const float scl = (z == 0) ? QSCALE : 1.0f;
#pragma unroll
        for (int j = 0; j < 4; ++j) {
            int n = n0 + wn + j * 16 + l16;
            float bb = bias[n];
#pragma unroll
            for (int i = 0; i < 4; ++i) {
                int mb = m0 + wm + i * 16 + quad * 4;
#pragma unroll
                for (int r = 0; r < 4; ++r)
                    C[(size_t)(mb + r) * 1024 + n] = f2bf((acc[i][j][r] + bb) * scl);
            }
        }
    }
}

// ---------------------------------------------------------------------------
// Output GEMM (R5 version): 64x128 tile, single-buffered, fp32 out.
// ---------------------------------------------------------------------------
__global__ __launch_bounds__(256) void gemm_out(
    const u16* __restrict__ A, const u16* __restrict__ Bt,
    const float* __restrict__ bias, float* __restrict__ C)
{
    __shared__ __align__(16) u16 sA[64 * 32];
    __shared__ __align__(16) u16 sB[128 * 32];
    const int tid = threadIdx.x;
    const int wave = tid >> 6, lane = tid & 63;
    const int quad = lane >> 4, l16 = lane & 15;
    const int m0 = blockIdx.x * 64, n0 = blockIdx.y * 128;
    const int wm = (wave & 1) * 32, wn = (wave >> 1) * 64;
    const int sw = (quad ^ ((l16 >> 1) & 3)) << 3;
    f32x4 acc[2][4] = {};

    for (int k0 = 0; k0 < 1024; k0 += 32) {
        __syncthreads();
        {
            int c = tid;
            int g = (c & 3) ^ ((c >> 3) & 3);
            const u16* gA = A + (size_t)(m0 + (c >> 2)) * 1024 + k0 + g * 8;
            async16(gA, (char*)sA + wave * 1024);
        }
#pragma unroll
        for (int r = 0; r < 2; ++r) {
            int c = tid + r * 256;
            int g = (c & 3) ^ ((c >> 3) & 3);
            const u16* gB = Bt + (size_t)(n0 + (c >> 2)) * 1024 + k0 + g * 8;
            async16(gB, (char*)sB + r * 4096 + wave * 1024);
        }
        __syncthreads();
        bf16x8 af[2], bfr[4];
#pragma unroll
        for (int i = 0; i < 2; ++i)
            af[i] = *(const bf16x8*)&sA[(wm + i * 16 + l16) * 32 + sw];
#pragma unroll
        for (int j = 0; j < 4; ++j)
            bfr[j] = *(const bf16x8*)&sB[(wn + j * 16 + l16) * 32 + sw];
#pragma unroll
        for (int i = 0; i < 2; ++i)
#pragma unroll
            for (int j = 0; j < 4; ++j)
                acc[i][j] = __builtin_amdgcn_mfma_f32_16x16x32_bf16(af[i], bfr[j], acc[i][j], 0, 0, 0);
    }
#pragma unroll
    for (int j = 0; j < 4; ++j) {
        int n = n0 + wn + j * 16 + l16;
        float bb = bias[n];
#pragma unroll
        for (int i = 0; i < 2; ++i) {
            int mb = m0 + wm + i * 16 + quad * 4;
#pragma unroll
            for (int r = 0; r < 4; ++r)
                C[(size_t)(mb + r) * 1024 + n] = acc[i][j][r] + bb;
        }
    }
}

// ---------------------------------------------------------------------------
// Attention v5: R5 structure widened to 512 threads / 8 waves / 128-q tile.
// Block: one (bh, 128-q tile); wave w owns q in [w*16, (w+1)*16) and iterates
// the FULL kv range (no cross-wave reduce). kv loop: 32 tiles of 64, start
// staggered per block (L2 hotspot fix). Shared double-buffered staging of
// K[64kv][64d] + V^T[64d][64kv] (one async16 per operand per lane); one
// barrier per tile; each staged tile feeds 8 waves (2x the MFMA per drain
// vs R5's 4-wave blocks). Per-wave math identical to R5: S^T = K@Q^T
// (16x16x32, C-layout row=kv col=q) -> exp2 -> pack P^T in-register as
// B-frag -> O^T += V^T@P^T (16x16x16). Epilogue: quad-butterfly rowsum,
// scale, direct bf16x4 stores.
// ---------------------------------------------------------------------------
__global__ __launch_bounds__(512, 4) void attn_kernel(
    const u16* __restrict__ Q,   // (B*T) x 1024, pre-scaled by QSCALE
    const u16* __restrict__ K,   // (B*T) x 1024
    const u16* __restrict__ Vt,  // (B*H) x 64 x 2048
    u16* __restrict__ Y)         // (B*T) x 1024
{
    __shared__ __align__(16) u16 sK[2][4096];   // [buf][64kv x 64d swizzled]
    __shared__ __align__(16) u16 sV[2][4096];   // [buf][64d x 64kv swizzled]

    const int tid = threadIdx.x;
    const int wave = tid >> 6, lane = tid & 63;
    const int quad = lane >> 4, l16 = lane & 15;

    const int bidx = blockIdx.x;
    const int bh = (bidx & 7) * 4 + ((bidx >> 3) & 3);   // XCD swizzle
    const int qt = bidx >> 5;            // 0..15 (128-q tiles)
    const int b = bh >> 4, h = bh & 15;
    const size_t qrow0 = (size_t)b * 2048 + qt * 128;
    const int st = ((qt << 1) | (bh & 1)) & 31;          // kv stagger

    // Q B-frags for this wave's 16 q rows: n=q=l16, k=d
    const size_t qrow = qrow0 + wave * 16 + l16;
    bf16x8 qf0 = *(const bf16x8*)&Q[qrow * 1024 + h * 64 + quad * 8];
    bf16x8 qf1 = *(const bf16x8*)&Q[qrow * 1024 + h * 64 + 32 + quad * 8];

    f32x4 oacc[4] = {};     // O^T [d=mt*16+quad*4+r][q=l16]
    float rowacc = 0.0f;

    const u16* Kbase = K + (size_t)b * 2048 * 1024 + h * 64;
    const u16* Vbase = Vt + (size_t)bh * 131072;

    // LDS read offsets (u16 elements), XOR-swizzled 16B-chunk addressing
    const int x7 = l16 & 7;
    int koff[4][2], voff[4][4];
#pragma unroll
    for (int ks = 0; ks < 4; ++ks)
#pragma unroll
        for (int kf = 0; kf < 2; ++kf)
            koff[ks][kf] = ((ks * 16 + l16) * 8 + ((kf * 4 + quad) ^ x7)) * 8;
#pragma unroll
    for (int mt = 0; mt < 4; ++mt)
#pragma unroll
        for (int ks = 0; ks < 4; ++ks)
            voff[mt][ks] = ((mt * 16 + l16) * 8 + ((ks * 2 + (quad >> 1)) ^ x7)) * 8 + (quad & 1) * 4;

    // staging: 512 threads cover a full 8KB tile in ONE async16 per operand.
    const int srow = tid >> 3;                       // 0..63
    const int g = (tid & 7) ^ (srow & 7);            // swizzled chunk

#define STAGE(kv0, buf)                                                          \
    {                                                                            \
        async16(Kbase + (size_t)((kv0) + srow) * 1024 + g * 8,                   \
                (char*)&sK[buf][0] + wave * 1024);                               \
        async16(Vbase + (size_t)srow * 2048 + (kv0) + g * 8,                     \
                (char*)&sV[buf][0] + wave * 1024);                               \
    }

    STAGE((st & 31) * 64, 0);

    for (int i = 0; i < 32; ++i) {
        __syncthreads();   // drains stage(i); buf[(i+1)&1] is free
        if (i < 31) {
            int kvn = ((st + i + 1) & 31) * 64;
            STAGE(kvn, (i + 1) & 1);
        }
        const u16* kb = &sK[i & 1][0];
        const u16* vb = &sV[i & 1][0];
#pragma unroll
        for (int ks = 0; ks < 4; ++ks) {
            bf16x8 kf0 = *(const bf16x8*)&kb[koff[ks][0]];
            bf16x8 kf1 = *(const bf16x8*)&kb[koff[ks][1]];
            f32x4 s = {0.f, 0.f, 0.f, 0.f};
            s = __builtin_amdgcn_mfma_f32_16x16x32_bf16(kf0, qf0, s, 0, 0, 0);
            s = __builtin_amdgcn_mfma_f32_16x16x32_bf16(kf1, qf1, s, 0, 0, 0);
            float p0 = __builtin_amdgcn_exp2f(s[0]);
            float p1 = __builtin_amdgcn_exp2f(s[1]);
            float p2 = __builtin_amdgcn_exp2f(s[2]);
            float p3 = __builtin_amdgcn_exp2f(s[3]);
            rowacc += (p0 + p1) + (p2 + p3);
            unsigned lo = __builtin_amdgcn_perm(fbits(p1) + 0x8000u, fbits(p0) + 0x8000u, 0x07060302u);
            unsigned hi = __builtin_amdgcn_perm(fbits(p3) + 0x8000u, fbits(p2) + 0x8000u, 0x07060302u);
            union { unsigned u[2]; bf16x4 v; } pku;
            pku.u[0] = lo; pku.u[1] = hi;
#pragma unroll
            for (int mt = 0; mt < 4; ++mt) {
                bf16x4 vv = *(const bf16x4*)&vb[voff[mt][ks]];
                oacc[mt] = __builtin_amdgcn_mfma_f32_16x16x16bf16_1k(vv, pku.v, oacc[mt], 0, 0, 0);
            }
        }
    }
#undef STAGE

    // rowsum butterfly over quads: every lane gets total for q=l16
    rowacc += __shfl_xor(rowacc, 16, 64);
    rowacc += __shfl_xor(rowacc, 32, 64);
    const float inv = 1.0f / rowacc;

    // write Y: lane holds (d=mt*16+quad*4+r, q=l16); 4 x 8B stores
#pragma unroll
    for (int mt = 0; mt < 4; ++mt) {
        bf16x4 o;
#pragma unroll
        for (int r = 0; r < 4; ++r) o[r] = (short)f2bf(oacc[mt][r] * inv);
        *(bf16x4*)&Y[qrow * 1024 + h * 64 + mt * 16 + quad * 4] = o;
    }
}

// ---------------------------------------------------------------------------
extern "C" void kernel_launch(void* const* d_in, const int* in_sizes, int n_in,
                              void* d_out, int out_size, void* d_ws, size_t ws_size,
                              hipStream_t stream) {
    const float* tgt = (const float*)d_in[0];
    const float* mem = (const float*)d_in[1];
    const float* Wq  = (const float*)d_in[2];
    const float* bq  = (const float*)d_in[3];
    const float* Wk  = (const float*)d_in[4];
    const float* bk  = (const float*)d_in[5];
    const float* Wv  = (const float*)d_in[6];
    const float* bv  = (const float*)d_in[7];
    const float* Wo  = (const float*)d_in[8];
    const float* bo  = (const float*)d_in[9];

    u16* ws = (u16*)d_ws;
    const size_t SZ = 4194304;          // elements per 4096x1024 bf16 buffer
    u16* Wt   = ws;                     // 4 x 1024x1024 bf16 (8 MB)
    u16* tgtb = ws + 4 * SZ;
    u16* memb = tgtb + SZ;
    u16* Qb   = memb + SZ;
    u16* Kb   = Qb + SZ;
    u16* Vtb  = Kb + SZ;                // 32 x 64 x 2048
    u16* Yb   = Vtb + SZ;
    float* out = (float*)d_out;

    prep<<<dim3(3072), 256, 0, stream>>>(tgt, mem, Wq, Wk, Wv, Wo, Wt, tgtb, memb);
    gemm_qkv<<<dim3(32, 8, 3), 256, 0, stream>>>(tgtb, memb, Wt, bq, bk, bv, Qb, Kb, Vtb);
    attn_kernel<<<dim3(512), 512, 0, stream>>>(Qb, Kb, Vtb, Yb);
    gemm_out<<<dim3(64, 8), 256, 0, stream>>>(Yb, Wt + 3 * (size_t)1048576, bo, out);
}